// Round 1
// baseline (290.817 us; speedup 1.0000x reference)
//
#include <hip/hip_runtime.h>

typedef __attribute__((ext_vector_type(8))) short short8;
typedef __attribute__((ext_vector_type(4))) float f32x4;

__device__ __forceinline__ unsigned short f2bf(float f) {
  unsigned int u = __float_as_uint(f);
  u += 0x7fffu + ((u >> 16) & 1u);   // round-to-nearest-even
  return (unsigned short)(u >> 16);
}
__device__ __forceinline__ float bf2f(unsigned short h) {
  return __uint_as_float(((unsigned int)h) << 16);
}
__device__ __forceinline__ short8 ld8(const unsigned short* p) {
  return *(const short8*)p;
}
#define MFMA(a, b, c) __builtin_amdgcn_mfma_f32_16x16x32_bf16((a), (b), (c), 0, 0, 0)

// ---------------------------------------------------------------------------
// Kernel 1: weight prep. Wcat^T hi/lo bf16 [192][256] (rows 0-31 Wq^T, 32-63
// Wk^T, 64-191 Wv^T), WoT bf16 [256][128].
// ---------------------------------------------------------------------------
__global__ void prep_weights(const float* __restrict__ Wq, const float* __restrict__ Wk,
                             const float* __restrict__ Wv, const float* __restrict__ Wo,
                             unsigned short* __restrict__ Wth, unsigned short* __restrict__ Wtl,
                             unsigned short* __restrict__ WoT) {
  int idx = blockIdx.x * 256 + threadIdx.x;
  if (idx < 192 * 256) {
    int o = idx >> 8, c = idx & 255;
    float w = (o < 32) ? Wq[c * 32 + o] : (o < 64) ? Wk[c * 32 + (o - 32)] : Wv[c * 128 + (o - 64)];
    unsigned short h = f2bf(w);
    Wth[idx] = h;
    Wtl[idx] = f2bf(w - bf2f(h));
  } else if (idx < 192 * 256 + 256 * 128) {
    int j = idx - 192 * 256;
    int c = j >> 7, d = j & 127;
    WoT[j] = f2bf(Wo[d * 256 + c]);
  }
}

// ---------------------------------------------------------------------------
// Kernel 2: QKV projection. 32 pixels/block. x staged to LDS as bf16 hi/lo
// (row pad +8 elems -> 528B stride, conflict-free b128 reads). q,k: 3-pass
// split MFMA then re-split to hi/lo bf16. v: 1-pass, written TRANSPOSED
// (swapped-operand MFMA) to Vt[b][128][4096].
// ---------------------------------------------------------------------------
__global__ __launch_bounds__(256) void proj_qkv(
    const float* __restrict__ x,
    const unsigned short* __restrict__ Wth, const unsigned short* __restrict__ Wtl,
    const float* __restrict__ bq, const float* __restrict__ bk, const float* __restrict__ bv,
    unsigned short* __restrict__ qh, unsigned short* __restrict__ qlo,
    unsigned short* __restrict__ kh, unsigned short* __restrict__ klo,
    unsigned short* __restrict__ Vt) {
  __shared__ unsigned short xsh[32][264];
  __shared__ unsigned short xsl[32][264];
  const int pix0 = blockIdx.x * 32;
  const int b = pix0 >> 12;
  const int nloc0 = pix0 & 4095;
  const int tid = threadIdx.x;

#pragma unroll
  for (int i = 0; i < 8; ++i) {
    int chunk = i * 256 + tid;
    int row = chunk >> 6;
    int c4 = (chunk & 63) * 4;
    float4 v = *(const float4*)(x + (size_t)(pix0 + row) * 256 + c4);
    unsigned short h0 = f2bf(v.x), h1 = f2bf(v.y), h2 = f2bf(v.z), h3 = f2bf(v.w);
    unsigned short l0 = f2bf(v.x - bf2f(h0)), l1 = f2bf(v.y - bf2f(h1));
    unsigned short l2 = f2bf(v.z - bf2f(h2)), l3 = f2bf(v.w - bf2f(h3));
    uint2 hp, lp;
    hp.x = (unsigned int)h0 | ((unsigned int)h1 << 16);
    hp.y = (unsigned int)h2 | ((unsigned int)h3 << 16);
    lp.x = (unsigned int)l0 | ((unsigned int)l1 << 16);
    lp.y = (unsigned int)l2 | ((unsigned int)l3 << 16);
    *(uint2*)&xsh[row][c4] = hp;
    *(uint2*)&xsl[row][c4] = lp;
  }
  __syncthreads();

  const int wave = tid >> 6, lane = tid & 63, l = lane & 15, qd = lane >> 4;
#pragma unroll
  for (int si = 0; si < 3; ++si) {
    const int sub = wave + si * 4;
    const int outc0 = sub * 16;
    if (si == 0) {  // q/k, split precision
      const int outc = outc0 + l;
      const float bias = (outc < 32) ? bq[outc] : bk[outc - 32];
      f32x4 acc[2];
      acc[0] = (f32x4){bias, bias, bias, bias};
      acc[1] = (f32x4){bias, bias, bias, bias};
#pragma unroll
      for (int kc = 0; kc < 8; ++kc) {
        short8 whf = ld8(Wth + (size_t)(outc0 + l) * 256 + kc * 32 + qd * 8);
        short8 wlf = ld8(Wtl + (size_t)(outc0 + l) * 256 + kc * 32 + qd * 8);
#pragma unroll
        for (int m = 0; m < 2; ++m) {
          short8 xhf = ld8(&xsh[m * 16 + l][kc * 32 + qd * 8]);
          short8 xlf = ld8(&xsl[m * 16 + l][kc * 32 + qd * 8]);
          acc[m] = MFMA(xlf, whf, acc[m]);
          acc[m] = MFMA(xhf, wlf, acc[m]);
          acc[m] = MFMA(xhf, whf, acc[m]);
        }
      }
#pragma unroll
      for (int m = 0; m < 2; ++m)
#pragma unroll
        for (int r = 0; r < 4; ++r) {
          const size_t pixel = (size_t)pix0 + m * 16 + 4 * qd + r;
          float val = acc[m][r];
          unsigned short h = f2bf(val);
          unsigned short lo = f2bf(val - bf2f(h));
          if (outc < 32) { qh[pixel * 32 + outc] = h; qlo[pixel * 32 + outc] = lo; }
          else           { kh[pixel * 32 + outc - 32] = h; klo[pixel * 32 + outc - 32] = lo; }
        }
    } else {  // v, transposed output
      const int dv0 = outc0 - 64;
      const float b0 = bv[dv0 + 4 * qd + 0], b1 = bv[dv0 + 4 * qd + 1];
      const float b2 = bv[dv0 + 4 * qd + 2], b3 = bv[dv0 + 4 * qd + 3];
      f32x4 acc[2];
      acc[0] = (f32x4){b0, b1, b2, b3};
      acc[1] = (f32x4){b0, b1, b2, b3};
#pragma unroll
      for (int kc = 0; kc < 8; ++kc) {
        short8 whf = ld8(Wth + (size_t)(outc0 + l) * 256 + kc * 32 + qd * 8);
#pragma unroll
        for (int m = 0; m < 2; ++m) {
          short8 xhf = ld8(&xsh[m * 16 + l][kc * 32 + qd * 8]);
          acc[m] = MFMA(whf, xhf, acc[m]);  // D = Wv^T * x^T  -> Vt layout
        }
      }
#pragma unroll
      for (int m = 0; m < 2; ++m)
#pragma unroll
        for (int r = 0; r < 4; ++r) {
          int dv = dv0 + 4 * qd + r;
          int n = nloc0 + m * 16 + l;
          Vt[(size_t)b * 128 * 4096 + (size_t)dv * 4096 + n] = f2bf(acc[m][r]);
        }
    }
  }
}

// ---------------------------------------------------------------------------
// Kernel 3: flash attention. 256 blocks (batch = blockIdx&7 -> XCD-pinned L2).
// 4 waves x 32 queries. No LDS, no barriers. S^T = K*Q^T via split-bf16
// (3 MFMA), online softmax with lane-local stats (m=lane&15), P-frag built
// via shuffles, O^T = Vt*P^T.
// ---------------------------------------------------------------------------
__global__ __launch_bounds__(256) void flash_attn(
    const unsigned short* __restrict__ qh, const unsigned short* __restrict__ qlo,
    const unsigned short* __restrict__ kh, const unsigned short* __restrict__ klo,
    const unsigned short* __restrict__ Vt, unsigned short* __restrict__ ao) {
  const int b = blockIdx.x & 7;
  const int tile = blockIdx.x >> 3;
  const int wave = threadIdx.x >> 6;
  const int lane = threadIdx.x & 63;
  const int l = lane & 15;
  const int qd = lane >> 4;
  const int m0 = tile * 128 + wave * 32;
  const unsigned short* qh_b = qh + (size_t)b * 4096 * 32;
  const unsigned short* ql_b = qlo + (size_t)b * 4096 * 32;
  const unsigned short* kh_b = kh + (size_t)b * 4096 * 32;
  const unsigned short* kl_b = klo + (size_t)b * 4096 * 32;
  const unsigned short* vt_b = Vt + (size_t)b * 128 * 4096;

  short8 qhf[2], qlf[2];
#pragma unroll
  for (int t = 0; t < 2; ++t) {
    int row = m0 + t * 16 + l;
    qhf[t] = ld8(qh_b + (size_t)row * 32 + qd * 8);
    qlf[t] = ld8(ql_b + (size_t)row * 32 + qd * 8);
  }
  f32x4 acc[2][8];
#pragma unroll
  for (int t = 0; t < 2; ++t)
#pragma unroll
    for (int s = 0; s < 8; ++s) acc[t][s] = (f32x4){0.f, 0.f, 0.f, 0.f};
  float mrun[2] = {-1e30f, -1e30f};
  float lrun[2] = {0.f, 0.f};

#pragma unroll 1
  for (int it = 0; it < 64; ++it) {
    const int n0 = it * 64;
    short8 khf[4], klf[4];
#pragma unroll
    for (int s = 0; s < 4; ++s) {
      int row = n0 + s * 16 + l;
      khf[s] = ld8(kh_b + (size_t)row * 32 + qd * 8);
      klf[s] = ld8(kl_b + (size_t)row * 32 + qd * 8);
    }
    short8 pfrag[2][2];
#pragma unroll
    for (int t = 0; t < 2; ++t) {
      f32x4 s4[4];
#pragma unroll
      for (int s = 0; s < 4; ++s) {
        f32x4 z = (f32x4){0.f, 0.f, 0.f, 0.f};
        z = MFMA(klf[s], qhf[t], z);   // k_lo * q_hi
        z = MFMA(khf[s], qlf[t], z);   // k_hi * q_lo
        z = MFMA(khf[s], qhf[t], z);   // k_hi * q_hi
        s4[s] = z;                     // S^T: lane holds (n = n0+s*16+4qd+r, m = l)
      }
      float mx = -1e30f;
#pragma unroll
      for (int s = 0; s < 4; ++s)
#pragma unroll
        for (int r = 0; r < 4; ++r) mx = fmaxf(mx, s4[s][r]);
      mx = fmaxf(mx, __shfl_xor(mx, 16));
      mx = fmaxf(mx, __shfl_xor(mx, 32));
      const float mnew = fmaxf(mrun[t], mx);
      float pv[4][4];
      float rs = 0.f;
#pragma unroll
      for (int s = 0; s < 4; ++s)
#pragma unroll
        for (int r = 0; r < 4; ++r) {
          float p = __expf(s4[s][r] - mnew);
          pv[s][r] = p;
          rs += p;
        }
      rs += __shfl_xor(rs, 16);
      rs += __shfl_xor(rs, 32);
      const float alpha = __expf(mrun[t] - mnew);
      lrun[t] = lrun[t] * alpha + rs;
      mrun[t] = mnew;
#pragma unroll
      for (int s = 0; s < 8; ++s)
#pragma unroll
        for (int r = 0; r < 4; ++r) acc[t][s][r] *= alpha;
      // Assemble P as B-frag of P^T: lane needs P(m=l, n = c*32 + qd*8 + j).
      // Owner: subtile 2c+(qd>>1), reg j&3, lane (2*(qd&1)+(j>>2))*16 + l.
#pragma unroll
      for (int c = 0; c < 2; ++c) {
        short8 pf;
#pragma unroll
        for (int j = 0; j < 8; ++j) {
          int src = ((2 * (qd & 1) + (j >> 2)) << 4) + l;
          float v0 = __shfl(pv[2 * c][j & 3], src);
          float v1 = __shfl(pv[2 * c + 1][j & 3], src);
          float v = (qd >> 1) ? v1 : v0;
          pf[j] = (short)f2bf(v);
        }
        pfrag[t][c] = pf;
      }
    }
#pragma unroll
    for (int s = 0; s < 8; ++s) {
      const unsigned short* vr = vt_b + (size_t)(s * 16 + l) * 4096 + n0 + qd * 8;
      short8 v0 = ld8(vr);
      short8 v1 = ld8(vr + 32);
      acc[0][s] = MFMA(v0, pfrag[0][0], acc[0][s]);
      acc[0][s] = MFMA(v1, pfrag[0][1], acc[0][s]);
      acc[1][s] = MFMA(v0, pfrag[1][0], acc[1][s]);
      acc[1][s] = MFMA(v1, pfrag[1][1], acc[1][s]);
    }
  }
#pragma unroll
  for (int t = 0; t < 2; ++t) {
    const float inv = 1.f / lrun[t];
    const size_t row = (size_t)b * 4096 + m0 + t * 16 + l;
#pragma unroll
    for (int s = 0; s < 8; ++s) {
      unsigned int w0 = (unsigned int)f2bf(acc[t][s][0] * inv) |
                        ((unsigned int)f2bf(acc[t][s][1] * inv) << 16);
      unsigned int w1 = (unsigned int)f2bf(acc[t][s][2] * inv) |
                        ((unsigned int)f2bf(acc[t][s][3] * inv) << 16);
      uint2 pkt; pkt.x = w0; pkt.y = w1;
      *(uint2*)(ao + row * 128 + s * 16 + qd * 4) = pkt;
    }
  }
}

// ---------------------------------------------------------------------------
// Kernel 4: output projection + bias + residual. out = ao @ Wo + bo + x.
// ---------------------------------------------------------------------------
__global__ __launch_bounds__(256) void out_proj(
    const unsigned short* __restrict__ ao, const unsigned short* __restrict__ WoT,
    const float* __restrict__ bo, const float* __restrict__ x, float* __restrict__ out) {
  const int pix0 = blockIdx.x * 64;
  const int wave = threadIdx.x >> 6, lane = threadIdx.x & 63, l = lane & 15, qd = lane >> 4;
  const int base = pix0 + wave * 16;
  short8 af[4];
#pragma unroll
  for (int kc = 0; kc < 4; ++kc)
    af[kc] = ld8(ao + (size_t)(base + l) * 128 + kc * 32 + qd * 8);
#pragma unroll
  for (int sub = 0; sub < 16; ++sub) {
    const int c = sub * 16 + l;
    const float bias = bo[c];
    f32x4 acc = (f32x4){bias, bias, bias, bias};
#pragma unroll
    for (int kc = 0; kc < 4; ++kc) {
      short8 wf = ld8(WoT + (size_t)c * 128 + kc * 32 + qd * 8);
      acc = MFMA(af[kc], wf, acc);
    }
#pragma unroll
    for (int r = 0; r < 4; ++r) {
      const size_t pixel = (size_t)base + 4 * qd + r;
      out[pixel * 256 + c] = acc[r] + x[pixel * 256 + c];
    }
  }
}

// ---------------------------------------------------------------------------
extern "C" void kernel_launch(void* const* d_in, const int* in_sizes, int n_in,
                              void* d_out, int out_size, void* d_ws, size_t ws_size,
                              hipStream_t stream) {
  const float* x  = (const float*)d_in[0];
  const float* Wq = (const float*)d_in[1];
  const float* bq = (const float*)d_in[2];
  const float* Wk = (const float*)d_in[3];
  const float* bk = (const float*)d_in[4];
  const float* Wv = (const float*)d_in[5];
  const float* bv = (const float*)d_in[6];
  const float* Wo = (const float*)d_in[7];
  const float* bo = (const float*)d_in[8];

  char* ws = (char*)d_ws;
  // Workspace map (bytes): total ~25.4 MB
  unsigned short* qh  = (unsigned short*)(ws + 0);          // 2 MB
  unsigned short* qlo = (unsigned short*)(ws + 2097152);    // 2 MB
  unsigned short* kh  = (unsigned short*)(ws + 4194304);    // 2 MB
  unsigned short* klo = (unsigned short*)(ws + 6291456);    // 2 MB
  unsigned short* Vt  = (unsigned short*)(ws + 8388608);    // 8 MB  [8][128][4096]
  unsigned short* ao  = (unsigned short*)(ws + 16777216);   // 8 MB  [32768][128]
  unsigned short* Wth = (unsigned short*)(ws + 25165824);   // 96 KB [192][256]
  unsigned short* Wtl = (unsigned short*)(ws + 25264128);   // 96 KB
  unsigned short* WoT = (unsigned short*)(ws + 25362432);   // 64 KB [256][128]

  prep_weights<<<320, 256, 0, stream>>>(Wq, Wk, Wv, Wo, Wth, Wtl, WoT);
  proj_qkv<<<1024, 256, 0, stream>>>(x, Wth, Wtl, bq, bk, bv, qh, qlo, kh, klo, Vt);
  flash_attn<<<256, 256, 0, stream>>>(qh, qlo, kh, klo, Vt, ao);
  out_proj<<<512, 256, 0, stream>>>(ao, WoT, bo, x, (float*)d_out);
}